// Round 17
// baseline (82.243 us; speedup 1.0000x reference)
//
#include <hip/hip_runtime.h>
#include <math.h>

#define DIM   2048
#define NEXP  64
#define TOPK  8
#define BM    64
#define NT    512
#define NBLK  256          // M / BM
#define RSTRIDE 132        // padded LDS row slot, floats (528 B, 16B-aligned)
#define BUF1  (BM * RSTRIDE)   // 8448 floats

typedef __attribute__((ext_vector_type(8)))  short bf16x8;
typedef __attribute__((ext_vector_type(16))) float f32x16;

#define MFMA(A, B, C) __builtin_amdgcn_mfma_f32_32x32x16_bf16(A, B, C, 0, 0, 0)
#define AS_BF(v) (*(const bf16x8*)&(v))

#define STR2(x) #x
#define STR(x) STR2(x)
#define GL16(dst, p, off) \
    asm volatile("global_load_dwordx4 %0, %1, off offset:" STR(off) \
                 : "=v"(dst) : "v"(p) : "memory")

__device__ inline unsigned int bfpack(float a, float b) {
    unsigned int ua = __float_as_uint(a), ub = __float_as_uint(b);
    unsigned int lo = (ua + 0x7FFFu + ((ua >> 16) & 1u)) >> 16;
    unsigned int hi = (ub + 0x7FFFu + ((ub >> 16) & 1u)) & 0xFFFF0000u;
    return hi | lo;
}
__device__ inline void split2pair(float a, float b, unsigned int& h, unsigned int& m) {
    h = bfpack(a, b);
    float ra = a - __uint_as_float(h << 16);
    float rb = b - __uint_as_float(h & 0xFFFF0000u);
    m = bfpack(ra, rb);
}

// w[e][k] f32 -> byte(T=k/16) = (T>>4)*65536 + (T&15)*4096 + (eh*2+term)*1024 + (kh*32+le)*16
__global__ __launch_bounds__(256) void prep_kernel(const float* __restrict__ w,
                                                   unsigned int* __restrict__ wpack) {
    const int u = blockIdx.x * 256 + threadIdx.x;   // 0..16383
    const int e = u >> 8, k8 = u & 255;
    const float4 v0 = *(const float4*)(w + (size_t)e * DIM + k8 * 8);
    const float4 v1 = *(const float4*)(w + (size_t)e * DIM + k8 * 8 + 4);
    unsigned int h[4], m[4];
    split2pair(v0.x, v0.y, h[0], m[0]);
    split2pair(v0.z, v0.w, h[1], m[1]);
    split2pair(v1.x, v1.y, h[2], m[2]);
    split2pair(v1.z, v1.w, h[3], m[3]);
    const int wv = k8 >> 5, t = (k8 >> 1) & 15, kh = k8 & 1;
    const int eh = e >> 5, le = e & 31;
    char* base = (char*)wpack + (size_t)wv * 65536 + t * 4096
               + (eh * 2) * 1024 + (kh * 32 + le) * 16;
    *(uint4*)(base)        = (uint4){h[0], h[1], h[2], h[3]};
    *(uint4*)(base + 1024) = (uint4){m[0], m[1], m[2], m[3]};
}

__global__ __launch_bounds__(NT, 4) void router_kernel(
    const float* __restrict__ x,
    const unsigned int* __restrict__ wpack,
    const float* __restrict__ bias,
    float* __restrict__ out,     // [M*8] scores | [M*8] idx(f32) | [64] counts(f32)
    int* __restrict__ histws,    // [NBLK][64]
    int M)
{
    // buf0 floats [0,8448), buf1 [8448,16896) = 67584 B; lg[64][66] aliases; hist after
    __shared__ __align__(16) char smem[67584 + 256];
    float* smemf = (float*)smem;
    int* hist = (int*)(smem + 67584);

    const int tid  = threadIdx.x;
    const int bid  = blockIdx.x;
    const int swz  = (bid & 7) * (NBLK / 8) + (bid >> 3);   // bijective XCD swizzle
    const int row0 = swz * BM;
    if (tid < NEXP) hist[tid] = 0;

    const int wv   = tid >> 6;      // wave: K16-tile wv within each K128 phase
    const int lane = tid & 63;
    const int lr   = lane & 31;
    const int kh   = lane >> 5;

    // ---- x staging: wave wv stages rows 8wv..8wv+7; GL16 i covers rows 8wv+2i,+1 (512 B each)
    const int l5  = lane >> 5;           // row parity within pair
    const int xr0 = 8 * wv;
    const float* xsrc0 = x + (size_t)(row0 + xr0 + 0 + l5) * DIM + lr * 4;
    const float* xsrc1 = x + (size_t)(row0 + xr0 + 2 + l5) * DIM + lr * 4;
    const float* xsrc2 = x + (size_t)(row0 + xr0 + 4 + l5) * DIM + lr * 4;
    const float* xsrc3 = x + (size_t)(row0 + xr0 + 6 + l5) * DIM + lr * 4;
    const int xo0 = (xr0 + 0 + l5) * RSTRIDE + lr * 4;
    const int xo1 = (xr0 + 2 + l5) * RSTRIDE + lr * 4;
    const int xo2 = (xr0 + 4 + l5) * RSTRIDE + lr * 4;
    const int xo3 = (xr0 + 6 + l5) * RSTRIDE + lr * 4;

    // ---- w: tile T = ph*8 + wv; byte(T) = (ph>>1)*65536 + (ph&1)*32768 + wv*4096 ----
    const char* wtb = (const char*)wpack + wv * 4096 + lane * 16;

    // ---- compute read offsets (floats): row-group g rows g*32+lr, k-local wv*16+kh*8 ----
    const int a0 = lr * RSTRIDE + wv * 16 + kh * 8;
    const int a1 = (32 + lr) * RSTRIDE + wv * 16 + kh * 8;

    f32x16 acc00 = {}, acc01 = {}, acc10 = {}, acc11 = {};
    uint4 xr0_, xr1_, xr2_, xr3_;
    uint4 w0h_, w0m_, w1h_, w1m_;

#define XLD(PH) do { \
        GL16(xr0_, xsrc0 + (PH) * 128, 0); \
        GL16(xr1_, xsrc1 + (PH) * 128, 0); \
        GL16(xr2_, xsrc2 + (PH) * 128, 0); \
        GL16(xr3_, xsrc3 + (PH) * 128, 0); \
    } while (0)

#define WLD(PH) do { \
        const char* p_ = wtb + ((PH) >> 1) * 65536 + ((PH) & 1) * 32768; \
        GL16(w0h_, p_, 0);    GL16(w0m_, p_, 1024); \
        GL16(w1h_, p_, 2048); GL16(w1m_, p_, 3072); \
    } while (0)

#define DSW(BUFO) do { \
        *(uint4*)(smemf + (BUFO) + xo0) = xr0_; \
        *(uint4*)(smemf + (BUFO) + xo1) = xr1_; \
        *(uint4*)(smemf + (BUFO) + xo2) = xr2_; \
        *(uint4*)(smemf + (BUFO) + xo3) = xr3_; \
    } while (0)

#define DOSPLIT(vlo, vhi, hv, mv) do { \
        unsigned int h_[4], m_[4]; \
        split2pair((vlo).x, (vlo).y, h_[0], m_[0]); \
        split2pair((vlo).z, (vlo).w, h_[1], m_[1]); \
        split2pair((vhi).x, (vhi).y, h_[2], m_[2]); \
        split2pair((vhi).z, (vhi).w, h_[3], m_[3]); \
        hv = (uint4){h_[0], h_[1], h_[2], h_[3]}; \
        mv = (uint4){m_[0], m_[1], m_[2], m_[3]}; \
    } while (0)

#define COMPUTE(BUFO) do { \
        float4 alo0_ = *(const float4*)(smemf + (BUFO) + a0); \
        float4 ahi0_ = *(const float4*)(smemf + (BUFO) + a0 + 4); \
        float4 alo1_ = *(const float4*)(smemf + (BUFO) + a1); \
        float4 ahi1_ = *(const float4*)(smemf + (BUFO) + a1 + 4); \
        uint4 ah_, am_; \
        DOSPLIT(alo0_, ahi0_, ah_, am_); \
        acc00 = MFMA(AS_BF(ah_), AS_BF(w0h_), acc00); \
        acc00 = MFMA(AS_BF(am_), AS_BF(w0h_), acc00); \
        acc00 = MFMA(AS_BF(ah_), AS_BF(w0m_), acc00); \
        acc01 = MFMA(AS_BF(ah_), AS_BF(w1h_), acc01); \
        acc01 = MFMA(AS_BF(am_), AS_BF(w1h_), acc01); \
        acc01 = MFMA(AS_BF(ah_), AS_BF(w1m_), acc01); \
        DOSPLIT(alo1_, ahi1_, ah_, am_); \
        acc10 = MFMA(AS_BF(ah_), AS_BF(w0h_), acc10); \
        acc10 = MFMA(AS_BF(am_), AS_BF(w0h_), acc10); \
        acc10 = MFMA(AS_BF(ah_), AS_BF(w0m_), acc10); \
        acc11 = MFMA(AS_BF(ah_), AS_BF(w1h_), acc11); \
        acc11 = MFMA(AS_BF(am_), AS_BF(w1h_), acc11); \
        acc11 = MFMA(AS_BF(ah_), AS_BF(w1m_), acc11); \
    } while (0)

#define VMW(N) do { asm volatile("s_waitcnt vmcnt(" STR(N) ")" ::: "memory"); \
                    __builtin_amdgcn_sched_barrier(0); } while (0)
#define LGK0 asm volatile("s_waitcnt lgkmcnt(0)" ::: "memory")
#define BAR __builtin_amdgcn_s_barrier()

// steady phase: XLD(p+1) | w(p) ready | COMPUTE(p) | WLD(p+1) | x(p+1) ready | DSW | BAR
#define PHASE(P, BUFC, BUFN) do { \
        XLD((P) + 1); VMW(4); COMPUTE(BUFC); WLD((P) + 1); VMW(4); \
        DSW(BUFN); LGK0; BAR; \
    } while (0)

    // prologue
    XLD(0); WLD(0);
    VMW(4);            // x(0) regs ready (oldest 4); w(0) still in flight
    DSW(0); LGK0; BAR;

    PHASE( 0, 0,    BUF1);
    PHASE( 1, BUF1, 0);
    PHASE( 2, 0,    BUF1);
    PHASE( 3, BUF1, 0);
    PHASE( 4, 0,    BUF1);
    PHASE( 5, BUF1, 0);
    PHASE( 6, 0,    BUF1);
    PHASE( 7, BUF1, 0);
    PHASE( 8, 0,    BUF1);
    PHASE( 9, BUF1, 0);
    PHASE(10, 0,    BUF1);
    PHASE(11, BUF1, 0);
    PHASE(12, 0,    BUF1);
    PHASE(13, BUF1, 0);
    PHASE(14, 0,    BUF1);
    VMW(0); COMPUTE(BUF1);     // phase 15

#undef PHASE
#undef VMW
#undef LGK0
#undef COMPUTE
#undef DOSPLIT
#undef DSW
#undef WLD
#undef XLD

    __syncthreads();

    // ---- split-K-8 reduce in LDS: 8 serialized wave-stages into lg[64][66] ----
    float* lg = smemf;
    for (int p = 0; p < 8; ++p) {
        if (wv == p) {
            #pragma unroll
            for (int r = 0; r < 16; ++r) {
                const int rr = (r & 3) + 8 * (r >> 2) + 4 * kh;   // verified C-layout (m74/m101)
                if (p == 0) {
                    lg[rr * 66 + lr]             = acc00[r];
                    lg[rr * 66 + 32 + lr]        = acc01[r];
                    lg[(32 + rr) * 66 + lr]      = acc10[r];
                    lg[(32 + rr) * 66 + 32 + lr] = acc11[r];
                } else {
                    lg[rr * 66 + lr]             += acc00[r];
                    lg[rr * 66 + 32 + lr]        += acc01[r];
                    lg[(32 + rr) * 66 + lr]      += acc10[r];
                    lg[(32 + rr) * 66 + 32 + lr] += acc11[r];
                }
            }
        }
        __syncthreads();
    }

    // ---- top-k + softmax + histogram (verified epilogue); wave wv: rows wv*8..+8 ----
    float* out_scores = out;
    float* out_idx    = out + (size_t)M * TOPK;

    for (int r8 = 0; r8 < 8; ++r8) {
        const int row = wv * 8 + r8;
        float vm = lg[row * 66 + lane] + bias[lane];
        float vals[TOPK];
        int   ids[TOPK];
        #pragma unroll
        for (int k = 0; k < TOPK; ++k) {
            float mv = vm;
            int   mi = lane;
            #pragma unroll
            for (int off = 32; off > 0; off >>= 1) {
                float ov = __shfl_xor(mv, off);
                int   oi = __shfl_xor(mi, off);
                if (ov > mv || (ov == mv && oi < mi)) { mv = ov; mi = oi; }
            }
            vals[k] = mv; ids[k] = mi;
            if (lane == mi) { vm = -INFINITY; atomicAdd(&hist[mi], 1); }
        }
        if (lane == 0) {
            const float m = vals[0];
            float e[TOPK];
            float ssum = 0.f;
            #pragma unroll
            for (int k = 0; k < TOPK; ++k) { e[k] = expf(vals[k] - m); ssum += e[k]; }
            const float inv = 1.0f / ssum;
            const size_t base = (size_t)(row0 + row) * TOPK;
            #pragma unroll
            for (int k = 0; k < TOPK; ++k) {
                out_scores[base + k] = e[k] * inv;
                out_idx[base + k]    = (float)ids[k];
            }
        }
    }

    __syncthreads();
    if (tid < NEXP) histws[bid * NEXP + tid] = hist[tid];
}

__global__ __launch_bounds__(512) void reduce_kernel(const int* __restrict__ histws,
                                                     float* __restrict__ counts) {
    __shared__ int partl[8][NEXP];
    const int t = threadIdx.x;
    const int e = t & 63, c = t >> 6;
    int sm = 0;
    for (int b = c; b < NBLK; b += 8) sm += histws[b * NEXP + e];
    partl[c][e] = sm;
    __syncthreads();
    if (t < NEXP) {
        int tot = 0;
        #pragma unroll
        for (int i = 0; i < 8; ++i) tot += partl[i][t];
        counts[t] = (float)tot;
    }
}

extern "C" void kernel_launch(void* const* d_in, const int* in_sizes, int n_in,
                              void* d_out, int out_size, void* d_ws, size_t ws_size,
                              hipStream_t stream) {
    const float* x    = (const float*)d_in[0];
    const float* w    = (const float*)d_in[1];
    const float* bias = (const float*)d_in[2];
    float* out = (float*)d_out;
    const int M = in_sizes[0] / DIM;   // 16384 rows

    unsigned int* wpack = (unsigned int*)d_ws;                      // 512 KB
    int* histws = (int*)((char*)d_ws + (1u << 20));                 // 64 KB
    float* out_counts = out + (size_t)2 * M * TOPK;

    prep_kernel<<<64, 256, 0, stream>>>(w, wpack);
    router_kernel<<<NBLK, NT, 0, stream>>>(x, wpack, bias, out, histws, M);
    reduce_kernel<<<1, 512, 0, stream>>>(histws, out_counts);
}